// Round 1
// baseline (1058.496 us; speedup 1.0000x reference)
//
#include <hip/hip_runtime.h>
#include <cstdint>
#include <cstddef>

// Problem: B=32, T=512, D=512, H=8, HD=64, TED=2048
// d_out (fp32): y[32*512*512] | series[32*8*512*512] | prior[...] | sigma_full[...]

typedef __attribute__((ext_vector_type(8))) __bf16 bf16x8;
typedef __attribute__((ext_vector_type(4))) float f32x4;

#define MFMA16(a, b, c) __builtin_amdgcn_mfma_f32_16x16x32_bf16((a), (b), (c), 0, 0, 0)

__device__ __forceinline__ void gload_lds16(const void* g, void* l) {
  __builtin_amdgcn_global_load_lds(
      (const __attribute__((address_space(1))) unsigned int*)g,
      (__attribute__((address_space(3))) unsigned int*)l, 16, 0, 0);
}

__device__ __forceinline__ float wave_sum(float v) {
#pragma unroll
  for (int off = 32; off; off >>= 1) v += __shfl_xor(v, off);
  return v;
}

// ---------------------------------------------------------------------------
// Weight conversion fp32->bf16 (Wq|Wk|Wv stacked 1536x512, out_W 512x512) and
// zero emb_acc (ws is poisoned 0xAA before every launch).
// ---------------------------------------------------------------------------
__global__ void k_convert(const float* __restrict__ Wq, const float* __restrict__ Wk,
                          const float* __restrict__ Wv, const float* __restrict__ Wo,
                          __bf16* __restrict__ wqkv, __bf16* __restrict__ wout,
                          float* __restrict__ embacc) {
  int i = blockIdx.x * 256 + threadIdx.x;  // grid 3072 -> 786432 threads exactly
  float v;
  if (i < 262144)      v = Wq[i];
  else if (i < 524288) v = Wk[i - 262144];
  else                 v = Wv[i - 524288];
  wqkv[i] = (__bf16)v;
  if (i < 262144) wout[i] = (__bf16)Wo[i];
  if (i < 32768)  embacc[i] = 0.f;
}

// ---------------------------------------------------------------------------
// LN1 (one wave per row) -> xn bf16; fused sigma = f(x @ Wsig) -> sig (B,T,H)
// ---------------------------------------------------------------------------
__global__ void k_ln1_sigma(const float* __restrict__ x, const float* __restrict__ g,
                            const float* __restrict__ be, const float* __restrict__ Wsig,
                            __bf16* __restrict__ xn, float* __restrict__ sig) {
  int tid = threadIdx.x, w = tid >> 6, l = tid & 63;
  int row = blockIdx.x * 4 + w;  // 0..16383
  const float* xr = x + (size_t)row * 512 + l * 8;
  f32x4 x0 = *(const f32x4*)xr, x1 = *(const f32x4*)(xr + 4);
  float s = 0.f, s2 = 0.f;
#pragma unroll
  for (int i = 0; i < 8; i++) { float v = (i < 4) ? x0[i] : x1[i - 4]; s += v; s2 += v * v; }
  s = wave_sum(s); s2 = wave_sum(s2);
  float m = s * (1.f / 512.f);
  float rstd = rsqrtf(s2 * (1.f / 512.f) - m * m + 1e-5f);
  const float* gr = g + l * 8; const float* br = be + l * 8;
  f32x4 g0 = *(const f32x4*)gr, g1 = *(const f32x4*)(gr + 4);
  f32x4 b0 = *(const f32x4*)br, b1 = *(const f32x4*)(br + 4);
  bf16x8 o;
#pragma unroll
  for (int i = 0; i < 8; i++) {
    float xv = (i < 4) ? x0[i] : x1[i - 4];
    float gv = (i < 4) ? g0[i] : g1[i - 4];
    float bv = (i < 4) ? b0[i] : b1[i - 4];
    o[i] = (__bf16)((xv - m) * rstd * gv + bv);
  }
  *(bf16x8*)(xn + (size_t)row * 512 + l * 8) = o;
  // sigma: u[h] = x . Wsig[:,h]  (Wsig is (512,8) row-major)
  float u[8] = {0, 0, 0, 0, 0, 0, 0, 0};
#pragma unroll
  for (int jj = 0; jj < 8; jj++) {
    float xv = (jj < 4) ? x0[jj] : x1[jj - 4];
    const float* wr = Wsig + (size_t)(l * 8 + jj) * 8;
    f32x4 w0 = *(const f32x4*)wr, w1 = *(const f32x4*)(wr + 4);
    u[0] += xv * w0[0]; u[1] += xv * w0[1]; u[2] += xv * w0[2]; u[3] += xv * w0[3];
    u[4] += xv * w1[0]; u[5] += xv * w1[1]; u[6] += xv * w1[2]; u[7] += xv * w1[3];
  }
#pragma unroll
  for (int hh = 0; hh < 8; hh++) u[hh] = wave_sum(u[hh]);
  if (l < 8) {
    float us = u[0];
#pragma unroll
    for (int hh = 1; hh < 8; hh++) if (l == hh) us = u[hh];
    float sg = 1.f / (1.f + __expf(-5.f * us)) + 1e-5f;
    // 3^sg - 1 via expm1 (avoids cancellation for tiny sg)
    float sv = expm1f(sg * 1.0986122886681098f);
    sig[(size_t)row * 8 + l] = sv;
  }
}

// ---------------------------------------------------------------------------
// 128x128x(K=512) bf16 MFMA GEMM, B given as (N,K) row-major ("B^T" form).
// Staging via global_load_lds width=16 directly into fragment order:
// chunk (rb|cb, ks) = 64 lanes x 16B, lane l holds row (16*t + (l&15)),
// k = ks*32 + (l>>4)*8 .. +8. ds_read_b128 back is lane-contiguous.
// EPI 0: store bf16 C.  EPI 1: store fp32 C + bias[j] + resid[i,j] (final y).
// ---------------------------------------------------------------------------
template <int EPI>
__global__ void k_gemm128(const __bf16* __restrict__ A, const __bf16* __restrict__ Bw,
                          __bf16* __restrict__ Cb, float* __restrict__ Cf,
                          const float* __restrict__ bias, const float* __restrict__ resid,
                          int ldc, int gridN) {
  int bid = blockIdx.x;
  int jn = bid % gridN, im = bid / gridN;
  int i0 = im * 128, j0 = jn * 128;
  int tid = threadIdx.x, w = tid >> 6, l = tid & 63, q = l >> 4, l15 = l & 15;
  int wm = w >> 1, wn = w & 1;
  __shared__ __attribute__((aligned(16))) __bf16 sAB[16384];  // A:[0,8192) B:[8192,16384)
  f32x4 acc[4][4] = {};
  for (int k0 = 0; k0 < 512; k0 += 64) {
    __syncthreads();
#pragma unroll
    for (int i = 0; i < 8; i++) {
      int c = w * 8 + i;
      if (c < 16) {
        int rb = c >> 1, ks = c & 1;
        const __bf16* gp = A + (size_t)(i0 + rb * 16 + l15) * 512 + k0 + ks * 32 + q * 8;
        gload_lds16(gp, &sAB[c * 512]);
      } else {
        int cc = c - 16; int cb = cc >> 1, ks = cc & 1;
        const __bf16* gp = Bw + (size_t)(j0 + cb * 16 + l15) * 512 + k0 + ks * 32 + q * 8;
        gload_lds16(gp, &sAB[8192 + cc * 512]);
      }
    }
    __syncthreads();
#pragma unroll
    for (int ks = 0; ks < 2; ks++) {
      bf16x8 af[4], bfr[4];
#pragma unroll
      for (int r4 = 0; r4 < 4; r4++) af[r4] = *(const bf16x8*)&sAB[((wm * 4 + r4) * 2 + ks) * 512 + l * 8];
#pragma unroll
      for (int c4 = 0; c4 < 4; c4++) bfr[c4] = *(const bf16x8*)&sAB[8192 + ((wn * 4 + c4) * 2 + ks) * 512 + l * 8];
#pragma unroll
      for (int r4 = 0; r4 < 4; r4++)
#pragma unroll
        for (int c4 = 0; c4 < 4; c4++)
          acc[r4][c4] = MFMA16(af[r4], bfr[c4], acc[r4][c4]);
    }
  }
  // C/D layout: col j = lane&15, row i = (lane>>4)*4 + reg  [m89/m91 verified]
#pragma unroll
  for (int r4 = 0; r4 < 4; r4++) {
#pragma unroll
    for (int c4 = 0; c4 < 4; c4++) {
      int j = j0 + wn * 64 + c4 * 16 + l15;
      int ib = i0 + wm * 64 + r4 * 16 + q * 4;
#pragma unroll
      for (int r = 0; r < 4; r++) {
        size_t off = (size_t)(ib + r) * ldc + j;
        if (EPI == 0) Cb[off] = (__bf16)acc[r4][c4][r];
        else          Cf[off] = acc[r4][c4][r] + bias[j] + resid[off];
      }
    }
  }
}

// ---------------------------------------------------------------------------
// V transpose: qkv cols [1024,1536) -> vt[b][h][d][t]  (k-contiguous for B-frags)
// ---------------------------------------------------------------------------
__global__ void k_vtrans(const __bf16* __restrict__ qkv, __bf16* __restrict__ vt) {
  int bid = blockIdx.x;  // 2048 = B*H*8
  int mt = bid & 7, bh = bid >> 3;
  int b = bh >> 3, h = bh & 7;
  __shared__ __bf16 tile[64 * 73];  // [m][d], pad 73 breaks bank alignment
  int tid = threadIdx.x;
  int row = tid >> 3, c8 = (tid & 7) * 8;
#pragma unroll
  for (int p = 0; p < 2; p++) {
    int rr = row + p * 32;
    int m = mt * 64 + rr;
    bf16x8 v = *(const bf16x8*)(qkv + (size_t)(b * 512 + m) * 1536 + 1024 + h * 64 + c8);
#pragma unroll
    for (int j = 0; j < 8; j++) tile[rr * 73 + c8 + j] = v[j];
  }
  __syncthreads();
  int m8 = (tid & 7) * 8;
#pragma unroll
  for (int p = 0; p < 2; p++) {
    int d = (tid >> 3) + p * 32;
    bf16x8 v;
#pragma unroll
    for (int j = 0; j < 8; j++) v[j] = tile[(m8 + j) * 73 + d];
    *(bf16x8*)(vt + ((size_t)(b * 8 + h) * 64 + d) * 512 + mt * 64 + m8) = v;
  }
}

// ---------------------------------------------------------------------------
// Fused attention. One WG per (b,h,row-quarter): 4 waves x 32 rows.
// Pass 1: rowsums of exp(QK^T/64). Pass 2: recompute, write series, P@V.
// Scores ~ +-0.2 so softmax w/o max-subtraction is numerically safe.
// ---------------------------------------------------------------------------
__global__ __launch_bounds__(256) void k_attn(const __bf16* __restrict__ qkv,
                                              const __bf16* __restrict__ vt,
                                              float* __restrict__ series,
                                              float* __restrict__ yout) {
  int bid = blockIdx.x;  // 1024 = B*H*4
  int bh = bid >> 2, rq = bid & 3;
  int b = bh >> 3, h = bh & 7;
  int tid = threadIdx.x, w = tid >> 6, l = tid & 63, q = l >> 4, l15 = l & 15;
  int n0 = rq * 128 + w * 32;
  __shared__ __attribute__((aligned(16))) __bf16 sK[8192];   // 16 chunks (mb,ks)
  __shared__ __attribute__((aligned(16))) __bf16 sV[8192];   // 16 chunks (nb,ks)
  __shared__ __attribute__((aligned(16))) __bf16 sP[8704];   // per-wave 16 x 136
  const float SC = 0.015625f;  // 1/64 (both sqrt scales folded)
  bf16x8 qf[2][2];
#pragma unroll
  for (int rb = 0; rb < 2; rb++)
#pragma unroll
    for (int ks = 0; ks < 2; ks++)
      qf[rb][ks] = *(const bf16x8*)(qkv + (size_t)(b * 512 + n0 + rb * 16 + l15) * 1536 + h * 64 + ks * 32 + q * 8);

  // ---- pass 1: row sums ----
  float rs0[4] = {0, 0, 0, 0}, rs1[4] = {0, 0, 0, 0};
  for (int mt = 0; mt < 4; mt++) {
    __syncthreads();
#pragma unroll
    for (int i = 0; i < 4; i++) {
      int c = w * 4 + i; int mb = c >> 1, ks = c & 1;
      const __bf16* gp = qkv + (size_t)(b * 512 + mt * 128 + mb * 16 + l15) * 1536 + 512 + h * 64 + ks * 32 + q * 8;
      gload_lds16(gp, &sK[c * 512]);
    }
    __syncthreads();
#pragma unroll
    for (int mb = 0; mb < 8; mb++) {
      f32x4 a0 = {0, 0, 0, 0}, a1 = {0, 0, 0, 0};
#pragma unroll
      for (int ks = 0; ks < 2; ks++) {
        bf16x8 kf = *(const bf16x8*)&sK[(mb * 2 + ks) * 512 + l * 8];
        a0 = MFMA16(qf[0][ks], kf, a0);
        a1 = MFMA16(qf[1][ks], kf, a1);
      }
#pragma unroll
      for (int r = 0; r < 4; r++) { rs0[r] += __expf(a0[r] * SC); rs1[r] += __expf(a1[r] * SC); }
    }
  }
  float inv0[4], inv1[4];
#pragma unroll
  for (int r = 0; r < 4; r++) {
    float v0 = rs0[r], v1 = rs1[r];
#pragma unroll
    for (int off = 8; off; off >>= 1) { v0 += __shfl_xor(v0, off); v1 += __shfl_xor(v1, off); }
    inv0[r] = 1.f / v0; inv1[r] = 1.f / v1;
  }
  // ---- pass 2: series + P@V ----
  f32x4 yacc[2][4] = {};
  size_t serb = (size_t)bh * 512 * 512;
  __bf16* pw = &sP[w * 2176];
  for (int mt = 0; mt < 4; mt++) {
    __syncthreads();
#pragma unroll
    for (int i = 0; i < 4; i++) {
      int c = w * 4 + i; int mb = c >> 1, ks = c & 1;
      const __bf16* gp = qkv + (size_t)(b * 512 + mt * 128 + mb * 16 + l15) * 1536 + 512 + h * 64 + ks * 32 + q * 8;
      gload_lds16(gp, &sK[c * 512]);
    }
#pragma unroll
    for (int i = 0; i < 4; i++) {
      int c = w * 4 + i; int nb = c >> 2, ks = c & 3;
      const __bf16* gp = vt + ((size_t)bh * 64 + nb * 16 + l15) * 512 + mt * 128 + ks * 32 + q * 8;
      gload_lds16(gp, &sV[c * 512]);
    }
    __syncthreads();
#pragma unroll
    for (int rb = 0; rb < 2; rb++) {
#pragma unroll
      for (int mb = 0; mb < 8; mb++) {
        f32x4 a = {0, 0, 0, 0};
#pragma unroll
        for (int ks = 0; ks < 2; ks++) {
          bf16x8 kf = *(const bf16x8*)&sK[(mb * 2 + ks) * 512 + l * 8];
          a = MFMA16(qf[rb][ks], kf, a);
        }
        int m = mt * 128 + mb * 16 + l15;
#pragma unroll
        for (int r = 0; r < 4; r++) {
          float p = __expf(a[r] * SC) * (rb ? inv1[r] : inv0[r]);
          int n = n0 + rb * 16 + q * 4 + r;
          series[serb + (size_t)n * 512 + m] = p;
          pw[(q * 4 + r) * 136 + mb * 16 + l15] = (__bf16)p;  // C-layout -> LDS
        }
      }
      // P (A-layout from LDS) @ V (B-frags from sV)
      bf16x8 pa[4];
#pragma unroll
      for (int ks = 0; ks < 4; ks++) pa[ks] = *(const bf16x8*)&pw[l15 * 136 + ks * 32 + q * 8];
#pragma unroll
      for (int nb = 0; nb < 4; nb++)
#pragma unroll
        for (int ks = 0; ks < 4; ks++) {
          bf16x8 vf = *(const bf16x8*)&sV[(nb * 4 + ks) * 512 + l * 8];
          yacc[rb][nb] = MFMA16(pa[ks], vf, yacc[rb][nb]);
        }
    }
  }
#pragma unroll
  for (int rb = 0; rb < 2; rb++)
#pragma unroll
    for (int nb = 0; nb < 4; nb++)
#pragma unroll
      for (int r = 0; r < 4; r++) {
        int n = n0 + rb * 16 + q * 4 + r;
        yout[(size_t)(b * 512 + n) * 512 + h * 64 + nb * 16 + l15] = yacc[rb][nb][r];
      }
}

// ---------------------------------------------------------------------------
// prior + sigma_full: pure streaming writes (536 MB), row-broadcast of sigma.
// ---------------------------------------------------------------------------
__global__ void k_prior(const float* __restrict__ sig, float* __restrict__ prior,
                        float* __restrict__ sigf) {
  int tid = threadIdx.x;
  int r = blockIdx.x * 2 + (tid >> 7);  // global (b,h,n) row, 0..131071
  int b = r >> 12, h = (r >> 9) & 7, n = r & 511;
  float sv = sig[(size_t)((b << 9) + n) * 8 + h];
  float c1 = -0.5f / (sv * sv);
  float c2 = 0.3989422804014327f / sv;  // 1/sqrt(2*pi)/sigma
  int m0 = (tid & 127) * 4;
  f32x4 pv, s4;
#pragma unroll
  for (int i = 0; i < 4; i++) {
    float d = (float)(n - (m0 + i));
    pv[i] = c2 * __expf(c1 * d * d);
    s4[i] = sv;
  }
  size_t base = (size_t)r * 512 + m0;
  *(f32x4*)(prior + base) = pv;
  *(f32x4*)(sigf + base) = s4;
}

// ---------------------------------------------------------------------------
// emb_out = silu(emb) @ emb_W  (32x2048 @ 2048x1024), partial sums via atomics
// ---------------------------------------------------------------------------
__global__ void k_embmm(const float* __restrict__ emb, const float* __restrict__ embW,
                        float* __restrict__ embacc) {
  int bid = blockIdx.x;  // 256 = 32 jc x 8 tc
  int jc = bid & 31, tc = bid >> 5;
  int tid = threadIdx.x;
  int jl = tid & 31, bg = tid >> 5;
  __shared__ float se[32][257];
  int t0 = tc * 256;
#pragma unroll
  for (int i = 0; i < 32; i++) {
    int idx = tid + 256 * i;
    int bb = idx >> 8, tt = idx & 255;
    float e = emb[(size_t)bb * 2048 + t0 + tt];
    se[bb][tt] = e / (1.f + __expf(-e));
  }
  __syncthreads();
  int j = jc * 32 + jl;
  float a0 = 0, a1 = 0, a2 = 0, a3 = 0;
  for (int tt = 0; tt < 256; tt += 4) {
    float w0 = embW[(size_t)(t0 + tt) * 1024 + j];
    float w1 = embW[(size_t)(t0 + tt + 1) * 1024 + j];
    float w2 = embW[(size_t)(t0 + tt + 2) * 1024 + j];
    float w3 = embW[(size_t)(t0 + tt + 3) * 1024 + j];
    const float* s0 = &se[bg * 4 + 0][tt];
    const float* s1 = &se[bg * 4 + 1][tt];
    const float* s2 = &se[bg * 4 + 2][tt];
    const float* s3 = &se[bg * 4 + 3][tt];
    a0 += w0 * s0[0] + w1 * s0[1] + w2 * s0[2] + w3 * s0[3];
    a1 += w0 * s1[0] + w1 * s1[1] + w2 * s1[2] + w3 * s1[3];
    a2 += w0 * s2[0] + w1 * s2[1] + w2 * s2[2] + w3 * s2[3];
    a3 += w0 * s3[0] + w1 * s3[1] + w2 * s3[2] + w3 * s3[3];
  }
  atomicAdd(&embacc[(size_t)(bg * 4 + 0) * 1024 + j], a0);
  atomicAdd(&embacc[(size_t)(bg * 4 + 1) * 1024 + j], a1);
  atomicAdd(&embacc[(size_t)(bg * 4 + 2) * 1024 + j], a2);
  atomicAdd(&embacc[(size_t)(bg * 4 + 3) * 1024 + j], a3);
}

// ---------------------------------------------------------------------------
// LN2 + stylization (scale/shift) + silu -> hs bf16 (one wave per row)
// ---------------------------------------------------------------------------
__global__ void k_ln2(const float* __restrict__ y, const float* __restrict__ g2,
                      const float* __restrict__ b2, const float* __restrict__ embacc,
                      const float* __restrict__ embb, __bf16* __restrict__ hs) {
  int tid = threadIdx.x, w = tid >> 6, l = tid & 63;
  int row = blockIdx.x * 4 + w;
  int b = row >> 9;
  const float* yr = y + (size_t)row * 512 + l * 8;
  f32x4 y0 = *(const f32x4*)yr, y1 = *(const f32x4*)(yr + 4);
  float s = 0.f, s2 = 0.f;
#pragma unroll
  for (int i = 0; i < 8; i++) { float v = (i < 4) ? y0[i] : y1[i - 4]; s += v; s2 += v * v; }
  s = wave_sum(s); s2 = wave_sum(s2);
  float m = s * (1.f / 512.f);
  float rstd = rsqrtf(s2 * (1.f / 512.f) - m * m + 1e-5f);
  int j = l * 8;
  f32x4 g0 = *(const f32x4*)(g2 + j), g1 = *(const f32x4*)(g2 + j + 4);
  f32x4 bb0 = *(const f32x4*)(b2 + j), bb1 = *(const f32x4*)(b2 + j + 4);
  const float* ea = embacc + (size_t)b * 1024;
  f32x4 sc0 = *(const f32x4*)(ea + j), sc1 = *(const f32x4*)(ea + j + 4);
  f32x4 sh0 = *(const f32x4*)(ea + 512 + j), sh1 = *(const f32x4*)(ea + 512 + j + 4);
  f32x4 e0 = *(const f32x4*)(embb + j), e1 = *(const f32x4*)(embb + j + 4);
  f32x4 f0 = *(const f32x4*)(embb + 512 + j), f1 = *(const f32x4*)(embb + 512 + j + 4);
  bf16x8 o;
#pragma unroll
  for (int i = 0; i < 8; i++) {
    float yv = (i < 4) ? y0[i] : y1[i - 4];
    float gv = (i < 4) ? g0[i] : g1[i - 4];
    float bv = (i < 4) ? bb0[i] : bb1[i - 4];
    float scv = ((i < 4) ? sc0[i] : sc1[i - 4]) + ((i < 4) ? e0[i] : e1[i - 4]);
    float shv = ((i < 4) ? sh0[i] : sh1[i - 4]) + ((i < 4) ? f0[i] : f1[i - 4]);
    float xv = (yv - m) * rstd * gv + bv;
    float v = xv * (1.f + scv) + shv;
    o[i] = (__bf16)(v / (1.f + __expf(-v)));
  }
  *(bf16x8*)(hs + (size_t)row * 512 + l * 8) = o;
}

// ---------------------------------------------------------------------------
extern "C" void kernel_launch(void* const* d_in, const int* in_sizes, int n_in,
                              void* d_out, int out_size, void* d_ws, size_t ws_size,
                              hipStream_t stream) {
  const float* x    = (const float*)d_in[0];
  const float* emb  = (const float*)d_in[1];
  const float* Wq   = (const float*)d_in[2];
  const float* Wk   = (const float*)d_in[3];
  const float* Wv   = (const float*)d_in[4];
  const float* Wsig = (const float*)d_in[5];
  const float* ln1g = (const float*)d_in[6];
  const float* ln1b = (const float*)d_in[7];
  const float* embW = (const float*)d_in[8];
  const float* embb = (const float*)d_in[9];
  const float* ln2g = (const float*)d_in[10];
  const float* ln2b = (const float*)d_in[11];
  const float* outW = (const float*)d_in[12];
  const float* outb = (const float*)d_in[13];
  (void)in_sizes; (void)n_in; (void)out_size; (void)ws_size;

  float* out      = (float*)d_out;
  float* o_y      = out;                // 8,388,608
  float* o_series = out + 8388608;      // 67,108,864
  float* o_prior  = out + 75497472;     // 67,108,864
  float* o_sigf   = out + 142606336;    // 67,108,864

  char* ws = (char*)d_ws;               // total scratch used: ~114.6 MB
  __bf16* xn     = (__bf16*)(ws + 0);          // 16 MB (reused as hs after QKV GEMM)
  __bf16* wqkv   = (__bf16*)(ws + 16777216);   // 1.5 MB
  __bf16* wout   = (__bf16*)(ws + 18350080);   // 0.5 MB
  float*  sig    = (float*)(ws + 18874368);    // 0.5 MB (B,T,H)
  float*  embacc = (float*)(ws + 19398656);    // 128 KB
  __bf16* qkv    = (__bf16*)(ws + 19529728);   // 48 MB (16384 x 1536)
  __bf16* vt     = (__bf16*)(ws + 69861376);   // 16 MB (B,H,64,512)
  float*  yattn  = (float*)(ws + 86638592);    // 32 MB
  __bf16* hs     = xn;

  k_convert<<<3072, 256, 0, stream>>>(Wq, Wk, Wv, outW, wqkv, wout, embacc);
  k_ln1_sigma<<<4096, 256, 0, stream>>>(x, ln1g, ln1b, Wsig, xn, sig);
  k_gemm128<0><<<1536, 256, 0, stream>>>(xn, wqkv, qkv, nullptr, nullptr, nullptr, 1536, 12);
  k_vtrans<<<2048, 256, 0, stream>>>(qkv, vt);
  k_attn<<<1024, 256, 0, stream>>>(qkv, vt, o_series, yattn);
  k_prior<<<65536, 256, 0, stream>>>(sig, o_prior, o_sigf);
  k_embmm<<<256, 256, 0, stream>>>(emb, embW, embacc);
  k_ln2<<<4096, 256, 0, stream>>>(yattn, ln2g, ln2b, embacc, embb, hs);
  k_gemm128<1><<<512, 256, 0, stream>>>(hs, wout, nullptr, o_y, outb, x, 512, 4);
}

// Round 2
// 1017.824 us; speedup vs baseline: 1.0400x; 1.0400x over previous
//
#include <hip/hip_runtime.h>
#include <cstdint>
#include <cstddef>

// Problem: B=32, T=512, D=512, H=8, HD=64, TED=2048
// d_out (fp32): y[32*512*512] | series[32*8*512*512] | prior[...] | sigma_full[...]

typedef __attribute__((ext_vector_type(8))) __bf16 bf16x8;
typedef __attribute__((ext_vector_type(4))) float f32x4;

#define MFMA16(a, b, c) __builtin_amdgcn_mfma_f32_16x16x32_bf16((a), (b), (c), 0, 0, 0)

__device__ __forceinline__ void gload_lds16(const void* g, void* l) {
  __builtin_amdgcn_global_load_lds(
      (const __attribute__((address_space(1))) unsigned int*)g,
      (__attribute__((address_space(3))) unsigned int*)l, 16, 0, 0);
}

__device__ __forceinline__ float wave_sum(float v) {
#pragma unroll
  for (int off = 32; off; off >>= 1) v += __shfl_xor(v, off);
  return v;
}

// ---------------------------------------------------------------------------
// Weight conversion fp32->bf16 (Wq|Wk|Wv stacked 1536x512, out_W 512x512) and
// zero emb_acc (ws is poisoned 0xAA before every launch).
// ---------------------------------------------------------------------------
__global__ void k_convert(const float* __restrict__ Wq, const float* __restrict__ Wk,
                          const float* __restrict__ Wv, const float* __restrict__ Wo,
                          __bf16* __restrict__ wqkv, __bf16* __restrict__ wout,
                          float* __restrict__ embacc) {
  int i = blockIdx.x * 256 + threadIdx.x;  // grid 3072 -> 786432 threads exactly
  float v;
  if (i < 262144)      v = Wq[i];
  else if (i < 524288) v = Wk[i - 262144];
  else                 v = Wv[i - 524288];
  wqkv[i] = (__bf16)v;
  if (i < 262144) wout[i] = (__bf16)Wo[i];
  if (i < 32768)  embacc[i] = 0.f;
}

// ---------------------------------------------------------------------------
// LN1 (one wave per row) -> xn bf16; fused sigma = f(x @ Wsig) -> sig (B,T,H)
// ---------------------------------------------------------------------------
__global__ void k_ln1_sigma(const float* __restrict__ x, const float* __restrict__ g,
                            const float* __restrict__ be, const float* __restrict__ Wsig,
                            __bf16* __restrict__ xn, float* __restrict__ sig) {
  int tid = threadIdx.x, w = tid >> 6, l = tid & 63;
  int row = blockIdx.x * 4 + w;  // 0..16383
  const float* xr = x + (size_t)row * 512 + l * 8;
  f32x4 x0 = *(const f32x4*)xr, x1 = *(const f32x4*)(xr + 4);
  float s = 0.f, s2 = 0.f;
#pragma unroll
  for (int i = 0; i < 8; i++) { float v = (i < 4) ? x0[i] : x1[i - 4]; s += v; s2 += v * v; }
  s = wave_sum(s); s2 = wave_sum(s2);
  float m = s * (1.f / 512.f);
  float rstd = rsqrtf(s2 * (1.f / 512.f) - m * m + 1e-5f);
  const float* gr = g + l * 8; const float* br = be + l * 8;
  f32x4 g0 = *(const f32x4*)gr, g1 = *(const f32x4*)(gr + 4);
  f32x4 b0 = *(const f32x4*)br, b1 = *(const f32x4*)(br + 4);
  bf16x8 o;
#pragma unroll
  for (int i = 0; i < 8; i++) {
    float xv = (i < 4) ? x0[i] : x1[i - 4];
    float gv = (i < 4) ? g0[i] : g1[i - 4];
    float bv = (i < 4) ? b0[i] : b1[i - 4];
    o[i] = (__bf16)((xv - m) * rstd * gv + bv);
  }
  *(bf16x8*)(xn + (size_t)row * 512 + l * 8) = o;
  // sigma: u[h] = x . Wsig[:,h]  (Wsig is (512,8) row-major)
  float u[8] = {0, 0, 0, 0, 0, 0, 0, 0};
#pragma unroll
  for (int jj = 0; jj < 8; jj++) {
    float xv = (jj < 4) ? x0[jj] : x1[jj - 4];
    const float* wr = Wsig + (size_t)(l * 8 + jj) * 8;
    f32x4 w0 = *(const f32x4*)wr, w1 = *(const f32x4*)(wr + 4);
    u[0] += xv * w0[0]; u[1] += xv * w0[1]; u[2] += xv * w0[2]; u[3] += xv * w0[3];
    u[4] += xv * w1[0]; u[5] += xv * w1[1]; u[6] += xv * w1[2]; u[7] += xv * w1[3];
  }
#pragma unroll
  for (int hh = 0; hh < 8; hh++) u[hh] = wave_sum(u[hh]);
  if (l < 8) {
    float us = u[0];
#pragma unroll
    for (int hh = 1; hh < 8; hh++) if (l == hh) us = u[hh];
    float sg = 1.f / (1.f + __expf(-5.f * us)) + 1e-5f;
    float sv = expm1f(sg * 1.0986122886681098f);  // 3^sg - 1
    sig[(size_t)row * 8 + l] = sv;
  }
}

// ---------------------------------------------------------------------------
// 128x128x(K=512) bf16 MFMA GEMM, B given as (N,K) row-major ("B^T" form).
// EPI 0: bf16 C via per-wave LDS-transpose epilogue -> coalesced dwordx4.
// EPI 1: fp32 C + bias[j] + resid[i,j] (final y), scalar epilogue.
// ---------------------------------------------------------------------------
template <int EPI>
__global__ void k_gemm128(const __bf16* __restrict__ A, const __bf16* __restrict__ Bw,
                          __bf16* __restrict__ Cb, float* __restrict__ Cf,
                          const float* __restrict__ bias, const float* __restrict__ resid,
                          int ldc, int gridN) {
  int bid = blockIdx.x;
  int jn = bid % gridN, im = bid / gridN;
  int i0 = im * 128, j0 = jn * 128;
  int tid = threadIdx.x, w = tid >> 6, l = tid & 63, q = l >> 4, l15 = l & 15;
  int wm = w >> 1, wn = w & 1;
  __shared__ __attribute__((aligned(16))) __bf16 sAB[16384];  // A:[0,8192) B:[8192,16384)
  f32x4 acc[4][4] = {};
  for (int k0 = 0; k0 < 512; k0 += 64) {
    __syncthreads();
#pragma unroll
    for (int i = 0; i < 8; i++) {
      int c = w * 8 + i;
      if (c < 16) {
        int rb = c >> 1, ks = c & 1;
        const __bf16* gp = A + (size_t)(i0 + rb * 16 + l15) * 512 + k0 + ks * 32 + q * 8;
        gload_lds16(gp, &sAB[c * 512]);
      } else {
        int cc = c - 16; int cb = cc >> 1, ks = cc & 1;
        const __bf16* gp = Bw + (size_t)(j0 + cb * 16 + l15) * 512 + k0 + ks * 32 + q * 8;
        gload_lds16(gp, &sAB[8192 + cc * 512]);
      }
    }
    __syncthreads();
#pragma unroll
    for (int ks = 0; ks < 2; ks++) {
      bf16x8 af[4], bfr[4];
#pragma unroll
      for (int r4 = 0; r4 < 4; r4++) af[r4] = *(const bf16x8*)&sAB[((wm * 4 + r4) * 2 + ks) * 512 + l * 8];
#pragma unroll
      for (int c4 = 0; c4 < 4; c4++) bfr[c4] = *(const bf16x8*)&sAB[8192 + ((wn * 4 + c4) * 2 + ks) * 512 + l * 8];
#pragma unroll
      for (int r4 = 0; r4 < 4; r4++)
#pragma unroll
        for (int c4 = 0; c4 < 4; c4++)
          acc[r4][c4] = MFMA16(af[r4], bfr[c4], acc[r4][c4]);
    }
  }
  // C/D layout: col j = lane&15, row i = (lane>>4)*4 + reg  [m89/m91 verified]
  if (EPI == 0) {
    // per-wave 64x64 bf16 tile in own sAB quarter -> coalesced 16B/lane stores
    __syncthreads();  // all waves done reading K-loop LDS
    __bf16* ct = &sAB[w * 4096];
#pragma unroll
    for (int r4 = 0; r4 < 4; r4++)
#pragma unroll
      for (int c4 = 0; c4 < 4; c4++)
#pragma unroll
        for (int r = 0; r < 4; r++)
          ct[(r4 * 16 + q * 4 + r) * 64 + c4 * 16 + l15] = (__bf16)acc[r4][c4][r];
    int r8 = l >> 3, c8 = (l & 7) * 8;
#pragma unroll
    for (int jj = 0; jj < 8; jj++) {
      int row = r8 + jj * 8;
      bf16x8 vv = *(const bf16x8*)&ct[row * 64 + c8];
      *(bf16x8*)&Cb[(size_t)(i0 + wm * 64 + row) * ldc + j0 + wn * 64 + c8] = vv;
    }
  } else {
#pragma unroll
    for (int r4 = 0; r4 < 4; r4++) {
#pragma unroll
      for (int c4 = 0; c4 < 4; c4++) {
        int j = j0 + wn * 64 + c4 * 16 + l15;
        int ib = i0 + wm * 64 + r4 * 16 + q * 4;
#pragma unroll
        for (int r = 0; r < 4; r++) {
          size_t off = (size_t)(ib + r) * ldc + j;
          Cf[off] = acc[r4][c4][r] + bias[j] + resid[off];
        }
      }
    }
  }
}

// ---------------------------------------------------------------------------
// V transpose: qkv cols [1024,1536) -> vt[b][h][d][t]  (k-contiguous for B-frags)
// ---------------------------------------------------------------------------
__global__ void k_vtrans(const __bf16* __restrict__ qkv, __bf16* __restrict__ vt) {
  int bid = blockIdx.x;  // 2048 = B*H*8
  int mt = bid & 7, bh = bid >> 3;
  int b = bh >> 3, h = bh & 7;
  __shared__ __bf16 tile[64 * 73];
  int tid = threadIdx.x;
  int row = tid >> 3, c8 = (tid & 7) * 8;
#pragma unroll
  for (int p = 0; p < 2; p++) {
    int rr = row + p * 32;
    int m = mt * 64 + rr;
    bf16x8 v = *(const bf16x8*)(qkv + (size_t)(b * 512 + m) * 1536 + 1024 + h * 64 + c8);
#pragma unroll
    for (int j = 0; j < 8; j++) tile[rr * 73 + c8 + j] = v[j];
  }
  __syncthreads();
  int m8 = (tid & 7) * 8;
#pragma unroll
  for (int p = 0; p < 2; p++) {
    int d = (tid >> 3) + p * 32;
    bf16x8 v;
#pragma unroll
    for (int j = 0; j < 8; j++) v[j] = tile[(m8 + j) * 73 + d];
    *(bf16x8*)(vt + ((size_t)(b * 8 + h) * 64 + d) * 512 + mt * 64 + m8) = v;
  }
}

// ---------------------------------------------------------------------------
// Fused attention + prior/sigma_full streaming writes.
// One WG per (b,h,row-quarter): 4 waves x 32 rows.
// Pass 1: rowsums of exp(QK^T/64) + prior/sigf writes (overlap stores w/ MFMA).
// Pass 2: recompute, write series (nt), P@V, y out as bf16.
// ---------------------------------------------------------------------------
__global__ __launch_bounds__(256) void k_attn(const __bf16* __restrict__ qkv,
                                              const __bf16* __restrict__ vt,
                                              const float* __restrict__ sig,
                                              float* __restrict__ series,
                                              float* __restrict__ prior,
                                              float* __restrict__ sigf,
                                              __bf16* __restrict__ yout) {
  int bid = blockIdx.x;  // 1024 = B*H*4
  int bh = bid >> 2, rq = bid & 3;
  int b = bh >> 3, h = bh & 7;
  int tid = threadIdx.x, w = tid >> 6, l = tid & 63, q = l >> 4, l15 = l & 15;
  int n0 = rq * 128 + w * 32;
  __shared__ __attribute__((aligned(16))) __bf16 sK[8192];
  __shared__ __attribute__((aligned(16))) __bf16 sV[8192];
  __shared__ __attribute__((aligned(16))) __bf16 sP[8704];  // per-wave 16 x 136
  __shared__ float sC1[128], sC2[128], sSg[128];
  const float SC = 0.015625f;  // 1/64 (both sqrt scales folded)

  if (tid < 128) {
    float sv = sig[(size_t)(b * 512 + rq * 128 + tid) * 8 + h];
    sSg[tid] = sv;
    sC1[tid] = -0.5f / (sv * sv);
    sC2[tid] = 0.3989422804014327f / sv;
  }

  bf16x8 qf[2][2];
#pragma unroll
  for (int rb = 0; rb < 2; rb++)
#pragma unroll
    for (int ks = 0; ks < 2; ks++)
      qf[rb][ks] = *(const bf16x8*)(qkv + (size_t)(b * 512 + n0 + rb * 16 + l15) * 1536 + h * 64 + ks * 32 + q * 8);

  // ---- pass 1: row sums + prior/sigma_full ----
  float rs0[4] = {0, 0, 0, 0}, rs1[4] = {0, 0, 0, 0};
  int prow = l >> 5, pm4 = (l & 31) * 4;
  for (int mt = 0; mt < 4; mt++) {
    __syncthreads();
#pragma unroll
    for (int i = 0; i < 4; i++) {
      int c = w * 4 + i; int mb = c >> 1, ks = c & 1;
      const __bf16* gp = qkv + (size_t)(b * 512 + mt * 128 + mb * 16 + l15) * 1536 + 512 + h * 64 + ks * 32 + q * 8;
      gload_lds16(gp, &sK[c * 512]);
    }
    __syncthreads();
#pragma unroll
    for (int mb = 0; mb < 8; mb++) {
      f32x4 a0 = {0, 0, 0, 0}, a1 = {0, 0, 0, 0};
#pragma unroll
      for (int ks = 0; ks < 2; ks++) {
        bf16x8 kf = *(const bf16x8*)&sK[(mb * 2 + ks) * 512 + l * 8];
        a0 = MFMA16(qf[0][ks], kf, a0);
        a1 = MFMA16(qf[1][ks], kf, a1);
      }
#pragma unroll
      for (int r = 0; r < 4; r++) { rs0[r] += __expf(a0[r] * SC); rs1[r] += __expf(a1[r] * SC); }
    }
    // prior/sigma_full slab: rows n0..n0+31, m in [mt*128, +128)
    {
      int mbase = mt * 128 + pm4;
#pragma unroll
      for (int j = 0; j < 16; j++) {
        int rr = 2 * j + prow;      // 0..31
        int ri = w * 32 + rr;       // 0..127
        int n = n0 + rr;
        float c1 = sC1[ri], c2 = sC2[ri], sv = sSg[ri];
        f32x4 pv, s4;
#pragma unroll
        for (int i = 0; i < 4; i++) {
          float d = (float)(n - (mbase + i));
          pv[i] = c2 * __expf(c1 * d * d);
          s4[i] = sv;
        }
        size_t off = ((size_t)bh * 512 + n) * 512 + mbase;
        __builtin_nontemporal_store(pv, (f32x4*)(prior + off));
        __builtin_nontemporal_store(s4, (f32x4*)(sigf + off));
      }
    }
  }
  float inv0[4], inv1[4];
#pragma unroll
  for (int r = 0; r < 4; r++) {
    float v0 = rs0[r], v1 = rs1[r];
#pragma unroll
    for (int off = 8; off; off >>= 1) { v0 += __shfl_xor(v0, off); v1 += __shfl_xor(v1, off); }
    inv0[r] = 1.f / v0; inv1[r] = 1.f / v1;
  }
  // ---- pass 2: series + P@V ----
  f32x4 yacc[2][4] = {};
  size_t serb = (size_t)bh * 512 * 512;
  __bf16* pw = &sP[w * 2176];
  for (int mt = 0; mt < 4; mt++) {
    __syncthreads();
#pragma unroll
    for (int i = 0; i < 4; i++) {
      int c = w * 4 + i; int mb = c >> 1, ks = c & 1;
      const __bf16* gp = qkv + (size_t)(b * 512 + mt * 128 + mb * 16 + l15) * 1536 + 512 + h * 64 + ks * 32 + q * 8;
      gload_lds16(gp, &sK[c * 512]);
    }
#pragma unroll
    for (int i = 0; i < 4; i++) {
      int c = w * 4 + i; int nb = c >> 2, ks = c & 3;
      const __bf16* gp = vt + ((size_t)bh * 64 + nb * 16 + l15) * 512 + mt * 128 + ks * 32 + q * 8;
      gload_lds16(gp, &sV[c * 512]);
    }
    __syncthreads();
#pragma unroll
    for (int rb = 0; rb < 2; rb++) {
#pragma unroll
      for (int mb = 0; mb < 8; mb++) {
        f32x4 a = {0, 0, 0, 0};
#pragma unroll
        for (int ks = 0; ks < 2; ks++) {
          bf16x8 kf = *(const bf16x8*)&sK[(mb * 2 + ks) * 512 + l * 8];
          a = MFMA16(qf[rb][ks], kf, a);
        }
        int m = mt * 128 + mb * 16 + l15;
#pragma unroll
        for (int r = 0; r < 4; r++) {
          float p = __expf(a[r] * SC) * (rb ? inv1[r] : inv0[r]);
          int n = n0 + rb * 16 + q * 4 + r;
          __builtin_nontemporal_store(p, series + serb + (size_t)n * 512 + m);
          pw[(q * 4 + r) * 136 + mb * 16 + l15] = (__bf16)p;  // C-layout -> LDS
        }
      }
      // P (A-layout from LDS) @ V (B-frags from sV)
      bf16x8 pa[4];
#pragma unroll
      for (int ks = 0; ks < 4; ks++) pa[ks] = *(const bf16x8*)&pw[l15 * 136 + ks * 32 + q * 8];
#pragma unroll
      for (int nb = 0; nb < 4; nb++)
#pragma unroll
        for (int ks = 0; ks < 4; ks++) {
          bf16x8 vf = *(const bf16x8*)&sV[(nb * 4 + ks) * 512 + l * 8];
          yacc[rb][nb] = MFMA16(pa[ks], vf, yacc[rb][nb]);
        }
    }
  }
#pragma unroll
  for (int rb = 0; rb < 2; rb++)
#pragma unroll
    for (int nb = 0; nb < 4; nb++)
#pragma unroll
      for (int r = 0; r < 4; r++) {
        int n = n0 + rb * 16 + q * 4 + r;
        yout[(size_t)(b * 512 + n) * 512 + h * 64 + nb * 16 + l15] = (__bf16)yacc[rb][nb][r];
      }
}

// ---------------------------------------------------------------------------
// emb_out = silu(emb) @ emb_W  (32x2048 @ 2048x1024), partial sums via atomics
// ---------------------------------------------------------------------------
__global__ void k_embmm(const float* __restrict__ emb, const float* __restrict__ embW,
                        float* __restrict__ embacc) {
  int bid = blockIdx.x;  // 256 = 32 jc x 8 tc
  int jc = bid & 31, tc = bid >> 5;
  int tid = threadIdx.x;
  int jl = tid & 31, bg = tid >> 5;
  __shared__ float se[32][257];
  int t0 = tc * 256;
#pragma unroll
  for (int i = 0; i < 32; i++) {
    int idx = tid + 256 * i;
    int bb = idx >> 8, tt = idx & 255;
    float e = emb[(size_t)bb * 2048 + t0 + tt];
    se[bb][tt] = e / (1.f + __expf(-e));
  }
  __syncthreads();
  int j = jc * 32 + jl;
  float a0 = 0, a1 = 0, a2 = 0, a3 = 0;
  for (int tt = 0; tt < 256; tt += 4) {
    float w0 = embW[(size_t)(t0 + tt) * 1024 + j];
    float w1 = embW[(size_t)(t0 + tt + 1) * 1024 + j];
    float w2 = embW[(size_t)(t0 + tt + 2) * 1024 + j];
    float w3 = embW[(size_t)(t0 + tt + 3) * 1024 + j];
    const float* s0 = &se[bg * 4 + 0][tt];
    const float* s1 = &se[bg * 4 + 1][tt];
    const float* s2 = &se[bg * 4 + 2][tt];
    const float* s3 = &se[bg * 4 + 3][tt];
    a0 += w0 * s0[0] + w1 * s0[1] + w2 * s0[2] + w3 * s0[3];
    a1 += w0 * s1[0] + w1 * s1[1] + w2 * s1[2] + w3 * s1[3];
    a2 += w0 * s2[0] + w1 * s2[1] + w2 * s2[2] + w3 * s2[3];
    a3 += w0 * s3[0] + w1 * s3[1] + w2 * s3[2] + w3 * s3[3];
  }
  atomicAdd(&embacc[(size_t)(bg * 4 + 0) * 1024 + j], a0);
  atomicAdd(&embacc[(size_t)(bg * 4 + 1) * 1024 + j], a1);
  atomicAdd(&embacc[(size_t)(bg * 4 + 2) * 1024 + j], a2);
  atomicAdd(&embacc[(size_t)(bg * 4 + 3) * 1024 + j], a3);
}

// ---------------------------------------------------------------------------
// LN2 + stylization (scale/shift) + silu -> hs bf16 (one wave per row)
// ---------------------------------------------------------------------------
__global__ void k_ln2(const __bf16* __restrict__ y, const float* __restrict__ g2,
                      const float* __restrict__ b2, const float* __restrict__ embacc,
                      const float* __restrict__ embb, __bf16* __restrict__ hs) {
  int tid = threadIdx.x, w = tid >> 6, l = tid & 63;
  int row = blockIdx.x * 4 + w;
  int b = row >> 9;
  bf16x8 yv8 = *(const bf16x8*)(y + (size_t)row * 512 + l * 8);
  float yv[8];
  float s = 0.f, s2 = 0.f;
#pragma unroll
  for (int i = 0; i < 8; i++) { yv[i] = (float)yv8[i]; s += yv[i]; s2 += yv[i] * yv[i]; }
  s = wave_sum(s); s2 = wave_sum(s2);
  float m = s * (1.f / 512.f);
  float rstd = rsqrtf(s2 * (1.f / 512.f) - m * m + 1e-5f);
  int j = l * 8;
  f32x4 g0 = *(const f32x4*)(g2 + j), g1 = *(const f32x4*)(g2 + j + 4);
  f32x4 bb0 = *(const f32x4*)(b2 + j), bb1 = *(const f32x4*)(b2 + j + 4);
  const float* ea = embacc + (size_t)b * 1024;
  f32x4 sc0 = *(const f32x4*)(ea + j), sc1 = *(const f32x4*)(ea + j + 4);
  f32x4 sh0 = *(const f32x4*)(ea + 512 + j), sh1 = *(const f32x4*)(ea + 512 + j + 4);
  f32x4 e0 = *(const f32x4*)(embb + j), e1 = *(const f32x4*)(embb + j + 4);
  f32x4 f0 = *(const f32x4*)(embb + 512 + j), f1 = *(const f32x4*)(embb + 512 + j + 4);
  bf16x8 o;
#pragma unroll
  for (int i = 0; i < 8; i++) {
    float gv = (i < 4) ? g0[i] : g1[i - 4];
    float bv = (i < 4) ? bb0[i] : bb1[i - 4];
    float scv = ((i < 4) ? sc0[i] : sc1[i - 4]) + ((i < 4) ? e0[i] : e1[i - 4]);
    float shv = ((i < 4) ? sh0[i] : sh1[i - 4]) + ((i < 4) ? f0[i] : f1[i - 4]);
    float xv = (yv[i] - m) * rstd * gv + bv;
    float v = xv * (1.f + scv) + shv;
    o[i] = (__bf16)(v / (1.f + __expf(-v)));
  }
  *(bf16x8*)(hs + (size_t)row * 512 + l * 8) = o;
}

// ---------------------------------------------------------------------------
extern "C" void kernel_launch(void* const* d_in, const int* in_sizes, int n_in,
                              void* d_out, int out_size, void* d_ws, size_t ws_size,
                              hipStream_t stream) {
  const float* x    = (const float*)d_in[0];
  const float* emb  = (const float*)d_in[1];
  const float* Wq   = (const float*)d_in[2];
  const float* Wk   = (const float*)d_in[3];
  const float* Wv   = (const float*)d_in[4];
  const float* Wsig = (const float*)d_in[5];
  const float* ln1g = (const float*)d_in[6];
  const float* ln1b = (const float*)d_in[7];
  const float* embW = (const float*)d_in[8];
  const float* embb = (const float*)d_in[9];
  const float* ln2g = (const float*)d_in[10];
  const float* ln2b = (const float*)d_in[11];
  const float* outW = (const float*)d_in[12];
  const float* outb = (const float*)d_in[13];
  (void)in_sizes; (void)n_in; (void)out_size; (void)ws_size;

  float* out      = (float*)d_out;
  float* o_y      = out;                // 8,388,608
  float* o_series = out + 8388608;      // 67,108,864
  float* o_prior  = out + 75497472;     // 67,108,864
  float* o_sigf   = out + 142606336;    // 67,108,864

  char* ws = (char*)d_ws;
  __bf16* xn     = (__bf16*)(ws + 0);          // 16 MB (reused as hs)
  __bf16* wqkv   = (__bf16*)(ws + 16777216);   // 1.5 MB
  __bf16* wout   = (__bf16*)(ws + 18350080);   // 0.5 MB
  float*  sig    = (float*)(ws + 18874368);    // 0.5 MB (B,T,H)
  float*  embacc = (float*)(ws + 19398656);    // 128 KB
  __bf16* qkv    = (__bf16*)(ws + 19529728);   // 48 MB (16384 x 1536)
  __bf16* vt     = (__bf16*)(ws + 69861376);   // 16 MB (B,H,64,512)
  __bf16* yattn  = (__bf16*)(ws + 86638592);   // 16 MB
  __bf16* hs     = xn;

  k_convert<<<3072, 256, 0, stream>>>(Wq, Wk, Wv, outW, wqkv, wout, embacc);
  k_ln1_sigma<<<4096, 256, 0, stream>>>(x, ln1g, ln1b, Wsig, xn, sig);
  k_gemm128<0><<<1536, 256, 0, stream>>>(xn, wqkv, qkv, nullptr, nullptr, nullptr, 1536, 12);
  k_vtrans<<<2048, 256, 0, stream>>>(qkv, vt);
  k_attn<<<1024, 256, 0, stream>>>(qkv, vt, sig, o_series, o_prior, o_sigf, yattn);
  k_embmm<<<256, 256, 0, stream>>>(emb, embW, embacc);
  k_ln2<<<4096, 256, 0, stream>>>(yattn, ln2g, ln2b, embacc, embb, hs);
  k_gemm128<1><<<512, 256, 0, stream>>>(hs, wout, nullptr, o_y, outb, x, 512, 4);
}